// Round 1
// baseline (1576.165 us; speedup 1.0000x reference)
//
#include <hip/hip_runtime.h>
#include <math.h>

#define BLK 512
#define CC 64
#define HH 256
#define WW 256
#define CPH 32
#define QC 192
#define HID 170
#define NPOS 100   // 10x10 halo tile

// ---- kernel 1 LDS layout (floats) ----
#define K1_XN   0        // 64*100 = 6400 (reused later: SC@0(128), ATT@128(2048), OW@2176(4096))
#define K1_QKV  6400     // 192*100 = 19200
#define K1_W    25600    // 192*65 = 12480  (stride 65: bank-conflict-free row-per-lane reads)
#define K1_TOT  38080    // 152,320 B
#define K1_SC   0
#define K1_ATT  128
#define K1_OW   2176

// ---- kernel 2 LDS layout ----
#define K2_XN 0          // 6400
#define K2_Y1 6400       // 6400
#define K2_Y2 12800      // 6400
#define K2_G  19200      // 4096
#define K2_TOT 23296     // 93,184 B

__device__ __forceinline__ void fma4(float4& a, float w, const float4& x) {
  a.x = fmaf(w, x.x, a.x); a.y = fmaf(w, x.y, a.y);
  a.z = fmaf(w, x.z, a.z); a.w = fmaf(w, x.w, a.w);
}

// load 10x10 halo of `src` (one batch image, 64ch) into lds[base + c*100 + p], layernorm it.
// OOB positions stay 0 (=> conv1x1 output 0 there = dwconv zero padding).
__device__ __forceinline__ void load_ln(const float* __restrict__ src,
                                        const float* __restrict__ ln_w,
                                        const float* __restrict__ ln_b,
                                        float* lds, int gy0, int gx0, int tid) {
  const size_t plane = (size_t)HH * WW;
  for (int idx = tid; idx < CC * NPOS; idx += BLK) {
    int c = idx / NPOS, p = idx - c * NPOS;
    int py = p / 10, px = p - py * 10;
    int gy = gy0 + py, gx = gx0 + px;
    float v = 0.f;
    if ((unsigned)gy < HH && (unsigned)gx < WW)
      v = src[(size_t)c * plane + gy * WW + gx];
    lds[c * NPOS + p] = v;
  }
  __syncthreads();
  for (int p = tid; p < NPOS; p += BLK) {
    int py = p / 10, px = p - py * 10;
    int gy = gy0 + py, gx = gx0 + px;
    if ((unsigned)gy < HH && (unsigned)gx < WW) {
      float s = 0.f, s2 = 0.f;
      for (int c = 0; c < CC; ++c) { float v = lds[c * NPOS + p]; s += v; s2 += v * v; }
      float mu = s * (1.f / 64.f);
      float var = s2 * (1.f / 64.f) - mu * mu;
      float rstd = rsqrtf(var + 1e-5f);
      for (int c = 0; c < CC; ++c) {
        float v = lds[c * NPOS + p];
        lds[c * NPOS + p] = (v - mu) * rstd * ln_w[c] + ln_b[c];
      }
    }
  }
  __syncthreads();
}

__global__ __launch_bounds__(BLK) void attn_kernel(
    const float* __restrict__ x, const float* __restrict__ ln_w, const float* __restrict__ ln_b,
    const float* __restrict__ qkv_w, const float* __restrict__ qkv_dw,
    const float* __restrict__ temp, const float* __restrict__ proj_w,
    const float* __restrict__ proj_b, float* __restrict__ x1) {
  __shared__ float lds[K1_TOT];
  const int tid = threadIdx.x;
  const int blk = blockIdx.x;
  const int b = blk >> 10;
  const int wy = (blk >> 5) & 31;
  const int wx = blk & 31;
  const int gy0 = wy * 8 - 1, gx0 = wx * 8 - 1;
  const size_t plane = (size_t)HH * WW;
  const float* xb = x + (size_t)b * CC * plane;

  // phase 1: halo load + LN1
  load_ln(xb, ln_w, ln_b, &lds[K1_XN], gy0, gx0, tid);

  // phase 2: qkv 1x1 conv (192 x 100, K=64), 2oc x 4pos register tiles
  for (int t = tid; t < 96 * 25; t += BLK) {
    int ocp = t / 25, pg = t - ocp * 25;
    int oc0 = ocp * 2, p0 = pg * 4;
    float4 a0 = make_float4(0, 0, 0, 0), a1 = make_float4(0, 0, 0, 0);
    const float4* w0 = (const float4*)(qkv_w + oc0 * 64);
    const float4* w1 = (const float4*)(qkv_w + oc0 * 64 + 64);
#pragma unroll 4
    for (int c4 = 0; c4 < 16; ++c4) {
      float4 wa = w0[c4], wb = w1[c4];
      const float* xp = &lds[K1_XN + c4 * 4 * NPOS + p0];
      float4 x0 = *(const float4*)(xp);
      float4 x1v = *(const float4*)(xp + NPOS);
      float4 x2 = *(const float4*)(xp + 2 * NPOS);
      float4 x3 = *(const float4*)(xp + 3 * NPOS);
      fma4(a0, wa.x, x0); fma4(a0, wa.y, x1v); fma4(a0, wa.z, x2); fma4(a0, wa.w, x3);
      fma4(a1, wb.x, x0); fma4(a1, wb.y, x1v); fma4(a1, wb.z, x2); fma4(a1, wb.w, x3);
    }
    *(float4*)&lds[K1_QKV + oc0 * NPOS + p0] = a0;
    *(float4*)&lds[K1_QKV + (oc0 + 1) * NPOS + p0] = a1;
  }
  __syncthreads();

  // phase 3: depthwise 3x3 into window (192 x 64), rows stride 65
  for (int idx = tid; idx < QC * 64; idx += BLK) {
    int oc = idx >> 6, wp = idx & 63;
    int hp = ((wp >> 3) + 1) * 10 + (wp & 7) + 1;
    const float* wd = qkv_dw + oc * 9;
    const float* src = &lds[K1_QKV + oc * NPOS];
    float acc = 0.f;
#pragma unroll
    for (int j = 0; j < 9; ++j) {
      int off = (j / 3 - 1) * 10 + (j % 3 - 1);
      acc = fmaf(wd[j], src[hp + off], acc);
    }
    lds[K1_W + oc * 65 + wp] = acc;
  }
  __syncthreads();

  // phase 4a: l2-norm scales for q (rows 0..63) and k (rows 64..127)
  if (tid < 128) {
    const float* r = &lds[K1_W + tid * 65];
    float s = 0.f;
#pragma unroll 8
    for (int d = 0; d < 64; ++d) s = fmaf(r[d], r[d], s);
    lds[K1_SC + tid] = 1.f / fmaxf(sqrtf(s), 1e-12f);
  }
  __syncthreads();

  // phase 4b: attn logits (2 heads x 32 x 32) + temperature
  float t0 = temp[0], t1 = temp[1];
  for (int idx = tid; idx < 2048; idx += BLK) {
    int h = idx >> 10, cq = (idx >> 5) & 31, e = idx & 31;
    const float* qr = &lds[K1_W + (h * CPH + cq) * 65];
    const float* kr = &lds[K1_W + (64 + h * CPH + e) * 65];
    float s = 0.f;
#pragma unroll 8
    for (int d = 0; d < 64; ++d) s = fmaf(qr[d], kr[d], s);
    s *= lds[K1_SC + h * CPH + cq] * lds[K1_SC + 64 + h * CPH + e] * (h ? t1 : t0);
    lds[K1_ATT + idx] = s;
  }
  __syncthreads();
  // softmax over e (rows = 64)
  if (tid < 64) {
    float* row = &lds[K1_ATT + tid * 32];
    float m = row[0];
    for (int e = 1; e < 32; ++e) m = fmaxf(m, row[e]);
    float s = 0.f;
    for (int e = 0; e < 32; ++e) { float v = __expf(row[e] - m); row[e] = v; s += v; }
    float inv = 1.f / s;
    for (int e = 0; e < 32; ++e) row[e] *= inv;
  }
  __syncthreads();

  // phase 4c: out = attn @ v  (ch=64 x d=64)
  for (int idx = tid; idx < 4096; idx += BLK) {
    int ch = idx >> 6, d = idx & 63;
    int h = ch >> 5;
    const float* ar = &lds[K1_ATT + ch * 32];
    const float* vb = &lds[K1_W + (128 + h * CPH) * 65 + d];
    float s = 0.f;
#pragma unroll 8
    for (int e = 0; e < 32; ++e) s = fmaf(ar[e], vb[e * 65], s);
    lds[K1_OW + ch * 64 + d] = s;
  }
  __syncthreads();

  // phase 5: proj 1x1 + bias + residual -> x1
  for (int idx = tid; idx < 4096; idx += BLK) {
    int o = idx >> 6, d = idx & 63;
    const float* wr = proj_w + o * 64;
    const float* ow = &lds[K1_OW + d];
    float s = proj_b[o];
#pragma unroll 8
    for (int ic = 0; ic < 64; ++ic) s = fmaf(wr[ic], ow[ic * 64], s);
    int gy = wy * 8 + (d >> 3), gx = wx * 8 + (d & 7);
    size_t gp = (size_t)(b * CC + o) * plane + gy * WW + gx;
    x1[gp] = xb[(size_t)o * plane + gy * WW + gx] + s;
  }
}

__global__ __launch_bounds__(BLK) void ffn_kernel(
    const float* __restrict__ x1, const float* __restrict__ ln_w, const float* __restrict__ ln_b,
    const float* __restrict__ pin_w, const float* __restrict__ dw_w,
    const float* __restrict__ pout_w, float* __restrict__ out) {
  __shared__ float lds[K2_TOT];
  const int tid = threadIdx.x;
  const int blk = blockIdx.x;
  const int b = blk >> 10;
  const int wy = (blk >> 5) & 31;
  const int wx = blk & 31;
  const int gy0 = wy * 8 - 1, gx0 = wx * 8 - 1;
  const size_t plane = (size_t)HH * WW;
  const float* xb = x1 + (size_t)b * CC * plane;

  // phase 1: halo load + LN2
  load_ln(xb, ln_w, ln_b, &lds[K2_XN], gy0, gx0, tid);

  const int o = tid >> 3;
  const int d0 = (tid & 7) * 8;
  float acc[8];
#pragma unroll
  for (int j = 0; j < 8; ++j) acc[j] = 0.f;

  const int chunkN[3] = {64, 64, 42};
  const int chunkP[3] = {0, 64, 128};
  for (int ci = 0; ci < 3; ++ci) {
    const int n = chunkN[ci], pc = chunkP[ci];
    // phase 2: pin 1x1 conv -> y1[n][100], y2[n][100] (row pairs x 4-pos tiles)
    for (int t = tid; t < n * 25; t += BLK) {
      int rp = t / 25, pg = t - rp * 25;
      int r0 = rp * 2, p0 = pg * 4;
      int wr = (r0 < n) ? (pc + r0) : (HID + pc + r0 - n);
      float* dst = &lds[(r0 < n ? K2_Y1 + r0 * NPOS : K2_Y2 + (r0 - n) * NPOS) + p0];
      const float4* w0 = (const float4*)(pin_w + wr * 64);
      const float4* w1 = (const float4*)(pin_w + wr * 64 + 64);
      float4 a0 = make_float4(0, 0, 0, 0), a1 = make_float4(0, 0, 0, 0);
#pragma unroll 4
      for (int c4 = 0; c4 < 16; ++c4) {
        float4 wa = w0[c4], wb = w1[c4];
        const float* xp = &lds[K2_XN + c4 * 4 * NPOS + p0];
        float4 x0 = *(const float4*)(xp);
        float4 x1v = *(const float4*)(xp + NPOS);
        float4 x2 = *(const float4*)(xp + 2 * NPOS);
        float4 x3 = *(const float4*)(xp + 3 * NPOS);
        fma4(a0, wa.x, x0); fma4(a0, wa.y, x1v); fma4(a0, wa.z, x2); fma4(a0, wa.w, x3);
        fma4(a1, wb.x, x0); fma4(a1, wb.y, x1v); fma4(a1, wb.z, x2); fma4(a1, wb.w, x3);
      }
      *(float4*)dst = a0;
      *(float4*)(dst + NPOS) = a1;
    }
    __syncthreads();
    // phase 3: dwconv3 on y1,y2 + exact gelu gate -> g[n][64]
    for (int idx = tid; idx < n * 64; idx += BLK) {
      int i = idx >> 6, wp = idx & 63;
      int hp = ((wp >> 3) + 1) * 10 + (wp & 7) + 1;
      const float* wa = dw_w + (pc + i) * 9;
      const float* wb = dw_w + (HID + pc + i) * 9;
      const float* s1 = &lds[K2_Y1 + i * NPOS];
      const float* s2 = &lds[K2_Y2 + i * NPOS];
      float va = 0.f, vb = 0.f;
#pragma unroll
      for (int j = 0; j < 9; ++j) {
        int off = (j / 3 - 1) * 10 + (j % 3 - 1);
        va = fmaf(wa[j], s1[hp + off], va);
        vb = fmaf(wb[j], s2[hp + off], vb);
      }
      float ge = 0.5f * va * (1.f + erff(va * 0.70710678118f));
      lds[K2_G + i * 64 + wp] = ge * vb;
    }
    __syncthreads();
    // phase 4: accumulate pout partial products in registers
    const float* wcol = pout_w + o * HID + pc;
    for (int i = 0; i < n; ++i) {
      float wv = wcol[i];
      const float* g = &lds[K2_G + i * 64 + d0];
      float4 g0 = *(const float4*)g;
      float4 g1 = *(const float4*)(g + 4);
      acc[0] = fmaf(wv, g0.x, acc[0]); acc[1] = fmaf(wv, g0.y, acc[1]);
      acc[2] = fmaf(wv, g0.z, acc[2]); acc[3] = fmaf(wv, g0.w, acc[3]);
      acc[4] = fmaf(wv, g1.x, acc[4]); acc[5] = fmaf(wv, g1.y, acc[5]);
      acc[6] = fmaf(wv, g1.z, acc[6]); acc[7] = fmaf(wv, g1.w, acc[7]);
    }
    __syncthreads();
  }

  // epilogue: residual + store (d = d0..d0+7 => window row tid&7, cols 0..7)
  {
    int gy = wy * 8 + (tid & 7);
    size_t base = (size_t)(b * CC + o) * plane + gy * WW + wx * 8;
    float4 r0 = *(const float4*)(x1 + base);
    float4 r1 = *(const float4*)(x1 + base + 4);
    float4 o0 = make_float4(acc[0] + r0.x, acc[1] + r0.y, acc[2] + r0.z, acc[3] + r0.w);
    float4 o1 = make_float4(acc[4] + r1.x, acc[5] + r1.y, acc[6] + r1.z, acc[7] + r1.w);
    *(float4*)(out + base) = o0;
    *(float4*)(out + base + 4) = o1;
  }
}

extern "C" void kernel_launch(void* const* d_in, const int* in_sizes, int n_in,
                              void* d_out, int out_size, void* d_ws, size_t ws_size,
                              hipStream_t stream) {
  const float* x      = (const float*)d_in[0];
  const float* ln1_w  = (const float*)d_in[1];
  const float* ln1_b  = (const float*)d_in[2];
  const float* qkv_w  = (const float*)d_in[3];
  const float* qkv_dw = (const float*)d_in[4];
  const float* temp   = (const float*)d_in[5];
  const float* proj_w = (const float*)d_in[6];
  const float* proj_b = (const float*)d_in[7];
  const float* ln2_w  = (const float*)d_in[8];
  const float* ln2_b  = (const float*)d_in[9];
  const float* pin_w  = (const float*)d_in[10];
  const float* dw_w   = (const float*)d_in[11];
  const float* pout_w = (const float*)d_in[12];
  float* out = (float*)d_out;
  float* x1  = (float*)d_ws;  // 4*64*256*256 fp32 = 67 MB

  attn_kernel<<<dim3(4096), dim3(BLK), 0, stream>>>(x, ln1_w, ln1_b, qkv_w, qkv_dw,
                                                    temp, proj_w, proj_b, x1);
  ffn_kernel<<<dim3(4096), dim3(BLK), 0, stream>>>(x1, ln2_w, ln2_b, pin_w, dw_w,
                                                   pout_w, out);
}

// Round 2
// 570.967 us; speedup vs baseline: 2.7605x; 2.7605x over previous
//
#include <hip/hip_runtime.h>
#include <math.h>

typedef __attribute__((ext_vector_type(8))) short short8;
typedef __attribute__((ext_vector_type(4))) float f32x4;

#define BLK 512
#define CC 64
#define HH 256
#define WW 256
#define HID 170
#define PLANE (HH*WW)

__device__ __forceinline__ unsigned short f2bf(float f) {
  unsigned u = __float_as_uint(f);
  u += 0x7FFFu + ((u >> 16) & 1u);
  return (unsigned short)(u >> 16);
}
__device__ __forceinline__ float bf2f(unsigned short h) {
  return __uint_as_float(((unsigned)h) << 16);
}
__device__ __forceinline__ float bf2f_lo(unsigned v) { return __uint_as_float(v << 16); }
__device__ __forceinline__ float bf2f_hi(unsigned v) { return __uint_as_float(v & 0xFFFF0000u); }

__device__ __forceinline__ f32x4 mfma16(short8 a, short8 b, f32x4 c) {
  return __builtin_amdgcn_mfma_f32_16x16x32_bf16(a, b, c, 0, 0, 0);
}
__device__ __forceinline__ uint2 pack4bf(f32x4 v) {
  uint2 r;
  r.x = (unsigned)f2bf(v[0]) | ((unsigned)f2bf(v[1]) << 16);
  r.y = (unsigned)f2bf(v[2]) | ((unsigned)f2bf(v[3]) << 16);
  return r;
}

// ======================= prepack (weights -> bf16 fragment order) ==========
// A-fragment layout: elem(mt,ks,lane,j) = W[mt*16 + (lane&15)][ks*32 + (lane>>4)*8 + j]
__global__ void prepack_kernel(const float* __restrict__ qkv_w, const float* __restrict__ proj_w,
                               const float* __restrict__ pin_w, const float* __restrict__ pout_w,
                               short* __restrict__ pq, short* __restrict__ pp,
                               short* __restrict__ pi, short* __restrict__ po) {
  int idx = blockIdx.x * 256 + threadIdx.x;
  if (idx < 12288) {  // qkv: 12 mtiles x 2 ksteps
    int j = idx & 7, ln = (idx >> 3) & 63, ks = (idx >> 9) & 1, mt = idx >> 10;
    int row = mt * 16 + (ln & 15), k = ks * 32 + (ln >> 4) * 8 + j;
    pq[idx] = (short)f2bf(qkv_w[row * 64 + k]);
  }
  if (idx < 4096) {   // proj: 4 x 2
    int j = idx & 7, ln = (idx >> 3) & 63, ks = (idx >> 9) & 1, mt = idx >> 10;
    int row = mt * 16 + (ln & 15), k = ks * 32 + (ln >> 4) * 8 + j;
    pp[idx] = (short)f2bf(proj_w[row * 64 + k]);
  }
  if (idx < 22528) {  // pin: 22 x 2, rows re-ordered into gate-pair chunks
    int j = idx & 7, ln = (idx >> 3) & 63, ks = (idx >> 9) & 1, mt = idx >> 10;
    int r = mt * 16 + (ln & 15), k = ks * 32 + (ln >> 4) * 8 + j;
    int c = r >> 7; if (c > 2) c = 2;
    int loc = r - c * 128;
    int half = (c < 2) ? 64 : 48, limit = (c < 2) ? 64 : 42;
    float v = 0.f;
    if (loc < half) { int i = loc; if (i < limit) v = pin_w[(c * 64 + i) * 64 + k]; }
    else { int i = loc - half; if (i < limit) v = pin_w[(HID + c * 64 + i) * 64 + k]; }
    pi[idx] = (short)f2bf(v);
  }
  if (idx < 12288) {  // pout: 4 mtiles x 6 ksteps (K padded 170->192)
    int j = idx & 7, ln = (idx >> 3) & 63, ks = (idx >> 9) % 6, mt = idx / 3072;
    int o = mt * 16 + (ln & 15), k = ks * 32 + (ln >> 4) * 8 + j;
    float v = (k < 170) ? pout_w[o * 170 + k] : 0.f;
    po[idx] = (short)f2bf(v);
  }
}

// ======================= attn kernel ========================================
// LDS regions (bytes):
#define A_QK    0        // 128 rows x 72 shorts = 18432  (q/k post-dwconv, [chan][d])
#define A_VT    18432    // 64 x 72 shorts = 9216         (v post-dwconv, [d][chan-128])
#define A_XST   0        // 64 x 101 f32 = 25856          (x halo stage; dead after LN)
#define A_XN    27648    // 112 x 64 shorts = 14336       (LN output, swizzled [pos][chan])
#define A_QKVT  41984    // 112 x 100 shorts = 22400      (qkv conv chunk, [pos][chan])
#define A_SCL   41984    // 128 f32 = 512                 (overlaps dead QKVT)
#define A_P     42496    // 64 x 33 f32 = 8448
#define A_PB    50944    // 64 x 40 shorts = 5120
#define A_OW    56064    // 64 x 72 shorts = 9216
#define A_TOT   65280

__global__ __launch_bounds__(BLK) void attn_kernel(
    const float* __restrict__ x, const float* __restrict__ ln_w, const float* __restrict__ ln_b,
    const float* __restrict__ qkv_dw, const float* __restrict__ temp,
    const float* __restrict__ proj_b,
    const short* __restrict__ pk_qkv, const short* __restrict__ pk_proj,
    unsigned short* __restrict__ x1) {
  __shared__ __align__(16) char smem[A_TOT];
  float* xst = (float*)(smem + A_XST);
  short* xn  = (short*)(smem + A_XN);
  short* qkvt = (short*)(smem + A_QKVT);
  short* qk  = (short*)(smem + A_QK);
  short* vt  = (short*)(smem + A_VT);
  float* scl = (float*)(smem + A_SCL);
  float* pP  = (float*)(smem + A_P);
  short* pB  = (short*)(smem + A_PB);
  short* ow  = (short*)(smem + A_OW);

  const int tid = threadIdx.x;
  const int lane = tid & 63;
  const int wid = tid >> 6;
  const int blk = blockIdx.x;
  const int b = blk >> 10, wy = (blk >> 5) & 31, wx = blk & 31;
  const int gy0 = wy * 8 - 1, gx0 = wx * 8 - 1;
  const float* xb = x + (size_t)b * CC * PLANE;

  // P1: stage 10x10 halo of x (fp32)
  for (int idx = tid; idx < CC * 100; idx += BLK) {
    int c = idx / 100, p = idx - c * 100;
    int py = p / 10, px = p - py * 10;
    int gy = gy0 + py, gx = gx0 + px;
    float v = 0.f;
    if ((unsigned)gy < HH && (unsigned)gx < WW) v = xb[c * PLANE + gy * WW + gx];
    xst[c * 101 + p] = v;
  }
  __syncthreads();

  // P2: LayerNorm -> xn (bf16, [pos][chan], XOR-swizzled 16B chunks)
  if (tid < 448) {
    int pos = tid >> 2, q = tid & 3;
    int p7 = pos & 7;
    if (pos < 100) {
      float s = 0.f, s2 = 0.f;
      float vv[16];
#pragma unroll
      for (int i = 0; i < 16; ++i) {
        float v = xst[(q * 16 + i) * 101 + pos];
        vv[i] = v; s += v; s2 += v * v;
      }
      s += __shfl_xor(s, 1); s2 += __shfl_xor(s2, 1);
      s += __shfl_xor(s, 2); s2 += __shfl_xor(s2, 2);
      float mu = s * (1.f / 64.f);
      float var = s2 * (1.f / 64.f) - mu * mu;
      float rstd = rsqrtf(var + 1e-5f);
      short8 o0, o1;
#pragma unroll
      for (int i = 0; i < 8; ++i) {
        o0[i] = (short)f2bf((vv[i] - mu) * rstd * ln_w[q * 16 + i] + ln_b[q * 16 + i]);
        o1[i] = (short)f2bf((vv[8 + i] - mu) * rstd * ln_w[q * 16 + 8 + i] + ln_b[q * 16 + 8 + i]);
      }
      *(short8*)(xn + pos * 64 + (((2 * q) ^ p7) * 8)) = o0;
      *(short8*)(xn + pos * 64 + (((2 * q + 1) ^ p7) * 8)) = o1;
    } else {
      short8 z = {0, 0, 0, 0, 0, 0, 0, 0};
      *(short8*)(xn + pos * 64 + (((2 * q) ^ p7) * 8)) = z;
      *(short8*)(xn + pos * 64 + (((2 * q + 1) ^ p7) * 8)) = z;
    }
  }
  __syncthreads();

  // P3: qkv GEMM + depthwise 3x3, two chunks of 96 channels
  for (int cc = 0; cc < 2; ++cc) {
    for (int f = wid; f < 42; f += 8) {   // 6 mtiles x 7 ntiles
      int mt = f / 7, nt = f - mt * 7;
      int gmt = cc * 6 + mt;
      f32x4 acc = {0.f, 0.f, 0.f, 0.f};
#pragma unroll
      for (int ks = 0; ks < 2; ++ks) {
        short8 a = *(const short8*)(pk_qkv + ((gmt * 2 + ks) * 64 + lane) * 8);
        int pos = nt * 16 + (lane & 15);
        short8 bb = *(const short8*)(xn + pos * 64 + (((ks * 4 + (lane >> 4)) ^ (pos & 7)) * 8));
        acc = mfma16(a, bb, acc);
      }
      int pos = nt * 16 + (lane & 15);
      int chb = mt * 16 + (lane >> 4) * 4;
      *(uint2*)(qkvt + pos * 100 + chb) = pack4bf(acc);
    }
    __syncthreads();
    // dwconv: 48 chan-pairs x 64 window positions
    for (int idx = tid; idx < 48 * 64; idx += BLK) {
      int pr = idx >> 6, wp = idx & 63;
      int hp = ((wp >> 3) + 1) * 10 + (wp & 7) + 1;
      int chl = pr * 2;
      int chg = cc * 96 + chl;
      const float* w0 = qkv_dw + chg * 9;
      const float* w1 = w0 + 9;
      float a0 = 0.f, a1 = 0.f;
#pragma unroll
      for (int t = 0; t < 9; ++t) {
        int off = (t / 3 - 1) * 10 + (t % 3 - 1);
        unsigned v = *(const unsigned*)(qkvt + (hp + off) * 100 + chl);
        a0 = fmaf(w0[t], bf2f_lo(v), a0);
        a1 = fmaf(w1[t], bf2f_hi(v), a1);
      }
      if (chg < 128) {
        qk[chg * 72 + wp] = (short)f2bf(a0);
        qk[(chg + 1) * 72 + wp] = (short)f2bf(a1);
      } else {
        unsigned pv = (unsigned)f2bf(a0) | ((unsigned)f2bf(a1) << 16);
        *(unsigned*)(vt + wp * 72 + (chg - 128)) = pv;
      }
    }
    __syncthreads();
  }

  // P4: inverse L2 norms for q (rows 0..63) and k (rows 64..127)
  if (tid < 128) {
    const short* r = qk + tid * 72;
    float s = 0.f;
#pragma unroll
    for (int i = 0; i < 8; ++i) {
      short8 v = *(const short8*)(r + i * 8);
#pragma unroll
      for (int j = 0; j < 8; ++j) { float f = bf2f((unsigned short)v[j]); s = fmaf(f, f, s); }
    }
    scl[tid] = 1.f / fmaxf(sqrtf(s), 1e-12f);
  }
  __syncthreads();

  // P5: QK^T logits (one 16x16 frag per wave; K=64 positions)
  {
    int h = wid >> 2, mt = (wid >> 1) & 1, nt = wid & 1;
    int arow = h * 32 + mt * 16;
    int brow = 64 + h * 32 + nt * 16;
    f32x4 acc = {0.f, 0.f, 0.f, 0.f};
#pragma unroll
    for (int ks = 0; ks < 2; ++ks) {
      short8 a = *(const short8*)(qk + (arow + (lane & 15)) * 72 + ks * 32 + (lane >> 4) * 8);
      short8 bb = *(const short8*)(qk + (brow + (lane & 15)) * 72 + ks * 32 + (lane >> 4) * 8);
      acc = mfma16(a, bb, acc);
    }
    float tf = temp[h];
    int e = nt * 16 + (lane & 15);
    float se = scl[64 + h * 32 + e] * tf;
    int cqb = h * 32 + mt * 16 + (lane >> 4) * 4;
#pragma unroll
    for (int j = 0; j < 4; ++j)
      pP[(cqb + j) * 33 + e] = acc[j] * scl[cqb + j] * se;
  }
  __syncthreads();

  // P6: softmax over e (64 rows x 32)
  if (tid < 64) {
    float* row = pP + tid * 33;
    float m = row[0];
#pragma unroll
    for (int e = 1; e < 32; ++e) m = fmaxf(m, row[e]);
    float s = 0.f;
    float ev[32];
#pragma unroll
    for (int e = 0; e < 32; ++e) { float v = __expf(row[e] - m); ev[e] = v; s += v; }
    float inv = 1.f / s;
#pragma unroll
    for (int gq = 0; gq < 4; ++gq) {
      short8 o;
#pragma unroll
      for (int j = 0; j < 8; ++j) o[j] = (short)f2bf(ev[gq * 8 + j] * inv);
      *(short8*)(pB + tid * 40 + gq * 8) = o;
    }
  }
  __syncthreads();

  // P7: PV (16 frags, 2 per wave; K=32)
#pragma unroll
  for (int r = 0; r < 2; ++r) {
    int f = wid + r * 8;
    int h = f >> 3, mt = (f >> 2) & 1, nt = f & 3;
    short8 a = *(const short8*)(pB + (h * 32 + mt * 16 + (lane & 15)) * 40 + (lane >> 4) * 8);
    short8 bb = *(const short8*)(vt + (nt * 16 + (lane & 15)) * 72 + h * 32 + (lane >> 4) * 8);
    f32x4 acc = {0.f, 0.f, 0.f, 0.f};
    acc = mfma16(a, bb, acc);
    int d = nt * 16 + (lane & 15);
    int chb = h * 32 + mt * 16 + (lane >> 4) * 4;
    *(uint2*)(ow + d * 72 + chb) = pack4bf(acc);
  }
  __syncthreads();

  // P8: proj + bias + residual -> x1 (bf16)
#pragma unroll
  for (int r = 0; r < 2; ++r) {
    int f = wid + r * 8;
    int mt = f >> 2, nt = f & 3;
    f32x4 acc = {0.f, 0.f, 0.f, 0.f};
#pragma unroll
    for (int ks = 0; ks < 2; ++ks) {
      short8 a = *(const short8*)(pk_proj + ((mt * 2 + ks) * 64 + lane) * 8);
      short8 bb = *(const short8*)(ow + (nt * 16 + (lane & 15)) * 72 + ks * 32 + (lane >> 4) * 8);
      acc = mfma16(a, bb, acc);
    }
    int pos = nt * 16 + (lane & 15);
    int gy = wy * 8 + (pos >> 3), gx = wx * 8 + (pos & 7);
    int ob = mt * 16 + (lane >> 4) * 4;
#pragma unroll
    for (int j = 0; j < 4; ++j) {
      int o = ob + j;
      size_t gp = (size_t)(b * CC + o) * PLANE + gy * WW + gx;
      float v = acc[j] + proj_b[o] + xb[(size_t)o * PLANE + gy * WW + gx];
      x1[gp] = f2bf(v);
    }
  }
}

// ======================= ffn kernel =========================================
#define F_Y12 0          // 112 x 132 shorts = 29568 (pin output chunk, [pos][chan])
#define F_XST 0          // 64 x 101 f32 = 25856 (overlaps; dead after LN)
#define F_XN  29568      // 112 x 64 shorts = 14336
#define F_G   43904      // 64 x 72 shorts = 9216 (gated, [pos][i])
#define F_TOT 53120

__global__ __launch_bounds__(BLK) void ffn_kernel(
    const unsigned short* __restrict__ x1, const float* __restrict__ ln_w, const float* __restrict__ ln_b,
    const float* __restrict__ dw_w,
    const short* __restrict__ pk_pin, const short* __restrict__ pk_pout,
    float* __restrict__ out) {
  __shared__ __align__(16) char smem[F_TOT];
  float* xst = (float*)(smem + F_XST);
  short* y12 = (short*)(smem + F_Y12);
  short* xn  = (short*)(smem + F_XN);
  short* g   = (short*)(smem + F_G);

  const int tid = threadIdx.x;
  const int lane = tid & 63;
  const int wid = tid >> 6;
  const int blk = blockIdx.x;
  const int b = blk >> 10, wy = (blk >> 5) & 31, wx = blk & 31;
  const int gy0 = wy * 8 - 1, gx0 = wx * 8 - 1;
  const unsigned short* xb = x1 + (size_t)b * CC * PLANE;

  // P1: stage halo (bf16 -> f32)
  for (int idx = tid; idx < CC * 100; idx += BLK) {
    int c = idx / 100, p = idx - c * 100;
    int py = p / 10, px = p - py * 10;
    int gy = gy0 + py, gx = gx0 + px;
    float v = 0.f;
    if ((unsigned)gy < HH && (unsigned)gx < WW) v = bf2f(xb[c * PLANE + gy * WW + gx]);
    xst[c * 101 + p] = v;
  }
  __syncthreads();

  // P2: LayerNorm -> xn
  if (tid < 448) {
    int pos = tid >> 2, q = tid & 3;
    int p7 = pos & 7;
    if (pos < 100) {
      float s = 0.f, s2 = 0.f;
      float vv[16];
#pragma unroll
      for (int i = 0; i < 16; ++i) {
        float v = xst[(q * 16 + i) * 101 + pos];
        vv[i] = v; s += v; s2 += v * v;
      }
      s += __shfl_xor(s, 1); s2 += __shfl_xor(s2, 1);
      s += __shfl_xor(s, 2); s2 += __shfl_xor(s2, 2);
      float mu = s * (1.f / 64.f);
      float var = s2 * (1.f / 64.f) - mu * mu;
      float rstd = rsqrtf(var + 1e-5f);
      short8 o0, o1;
#pragma unroll
      for (int i = 0; i < 8; ++i) {
        o0[i] = (short)f2bf((vv[i] - mu) * rstd * ln_w[q * 16 + i] + ln_b[q * 16 + i]);
        o1[i] = (short)f2bf((vv[8 + i] - mu) * rstd * ln_w[q * 16 + 8 + i] + ln_b[q * 16 + 8 + i]);
      }
      *(short8*)(xn + pos * 64 + (((2 * q) ^ p7) * 8)) = o0;
      *(short8*)(xn + pos * 64 + (((2 * q + 1) ^ p7) * 8)) = o1;
    } else {
      short8 z = {0, 0, 0, 0, 0, 0, 0, 0};
      *(short8*)(xn + pos * 64 + (((2 * q) ^ p7) * 8)) = z;
      *(short8*)(xn + pos * 64 + (((2 * q + 1) ^ p7) * 8)) = z;
    }
  }
  __syncthreads();

  f32x4 acc0 = {0.f, 0.f, 0.f, 0.f}, acc1 = {0.f, 0.f, 0.f, 0.f};

  for (int cc2 = 0; cc2 < 3; ++cc2) {
    const int MT = (cc2 < 2) ? 8 : 6;
    const int mbase = cc2 * 8;
    // pin GEMM chunk -> y12 [pos][chan]
    for (int f = wid; f < MT * 7; f += 8) {
      int mt = f / 7, nt = f - mt * 7;
      int gmt = mbase + mt;
      f32x4 acc = {0.f, 0.f, 0.f, 0.f};
#pragma unroll
      for (int ks = 0; ks < 2; ++ks) {
        short8 a = *(const short8*)(pk_pin + ((gmt * 2 + ks) * 64 + lane) * 8);
        int pos = nt * 16 + (lane & 15);
        short8 bb = *(const short8*)(xn + pos * 64 + (((ks * 4 + (lane >> 4)) ^ (pos & 7)) * 8));
        acc = mfma16(a, bb, acc);
      }
      int pos = nt * 16 + (lane & 15);
      int chb = mt * 16 + (lane >> 4) * 4;
      *(uint2*)(y12 + pos * 132 + chb) = pack4bf(acc);
    }
    __syncthreads();
    // dwconv + exact-GELU gate -> g [pos][i]
    const int half = (cc2 < 2) ? 64 : 48;
    const int npg = half >> 1;
    for (int idx = tid; idx < npg * 64; idx += BLK) {
      int pr = idx >> 6, wp = idx & 63;
      int hp = ((wp >> 3) + 1) * 10 + (wp & 7) + 1;
      int i0 = pr * 2;
      const float* wa = dw_w + (64 * cc2 + i0) * 9;
      const float* wb = wa + 9;
      const float* wc = dw_w + (HID + 64 * cc2 + i0) * 9;
      const float* wdd = wc + 9;
      float a0 = 0.f, a1 = 0.f, b0 = 0.f, b1 = 0.f;
#pragma unroll
      for (int t = 0; t < 9; ++t) {
        int off = (t / 3 - 1) * 10 + (t % 3 - 1);
        unsigned v1 = *(const unsigned*)(y12 + (hp + off) * 132 + i0);
        unsigned v2 = *(const unsigned*)(y12 + (hp + off) * 132 + half + i0);
        a0 = fmaf(wa[t], bf2f_lo(v1), a0);
        a1 = fmaf(wb[t], bf2f_hi(v1), a1);
        b0 = fmaf(wc[t], bf2f_lo(v2), b0);
        b1 = fmaf(wdd[t], bf2f_hi(v2), b1);
      }
      float g0 = 0.5f * a0 * (1.f + erff(a0 * 0.70710678118654752f)) * b0;
      float g1 = 0.5f * a1 * (1.f + erff(a1 * 0.70710678118654752f)) * b1;
      unsigned pv = (unsigned)f2bf(g0) | ((unsigned)f2bf(g1) << 16);
      *(unsigned*)(g + wp * 72 + i0) = pv;
    }
    __syncthreads();
    // pout partial GEMM (accumulate across chunks in registers)
    {
      int f0 = wid;
      int mt = f0 >> 2, nt = f0 & 3;
#pragma unroll
      for (int ks = 0; ks < 2; ++ks) {
        int gks = cc2 * 2 + ks;
        short8 a = *(const short8*)(pk_pout + ((mt * 6 + gks) * 64 + lane) * 8);
        short8 bb = *(const short8*)(g + (nt * 16 + (lane & 15)) * 72 + ks * 32 + (lane >> 4) * 8);
        acc0 = mfma16(a, bb, acc0);
      }
      int f1 = wid + 8;
      mt = f1 >> 2; nt = f1 & 3;
#pragma unroll
      for (int ks = 0; ks < 2; ++ks) {
        int gks = cc2 * 2 + ks;
        short8 a = *(const short8*)(pk_pout + ((mt * 6 + gks) * 64 + lane) * 8);
        short8 bb = *(const short8*)(g + (nt * 16 + (lane & 15)) * 72 + ks * 32 + (lane >> 4) * 8);
        acc1 = mfma16(a, bb, acc1);
      }
    }
    __syncthreads();
  }

  // epilogue: + residual -> out (fp32)
#pragma unroll
  for (int r = 0; r < 2; ++r) {
    int f = wid + r * 8;
    int mt = f >> 2, nt = f & 3;
    f32x4 acc = r ? acc1 : acc0;
    int pos = nt * 16 + (lane & 15);
    int gy = wy * 8 + (pos >> 3), gx = wx * 8 + (pos & 7);
    int ob = mt * 16 + (lane >> 4) * 4;
#pragma unroll
    for (int j = 0; j < 4; ++j) {
      int o = ob + j;
      size_t gp = (size_t)(b * CC + o) * PLANE + gy * WW + gx;
      out[gp] = acc[j] + bf2f(x1[gp]);
    }
  }
}

// ======================= launch =============================================
extern "C" void kernel_launch(void* const* d_in, const int* in_sizes, int n_in,
                              void* d_out, int out_size, void* d_ws, size_t ws_size,
                              hipStream_t stream) {
  const float* x      = (const float*)d_in[0];
  const float* ln1_w  = (const float*)d_in[1];
  const float* ln1_b  = (const float*)d_in[2];
  const float* qkv_w  = (const float*)d_in[3];
  const float* qkv_dw = (const float*)d_in[4];
  const float* temp   = (const float*)d_in[5];
  const float* proj_w = (const float*)d_in[6];
  const float* proj_b = (const float*)d_in[7];
  const float* ln2_w  = (const float*)d_in[8];
  const float* ln2_b  = (const float*)d_in[9];
  const float* pin_w  = (const float*)d_in[10];
  const float* dw_w   = (const float*)d_in[11];
  const float* pout_w = (const float*)d_in[12];
  float* out = (float*)d_out;

  unsigned short* x1 = (unsigned short*)d_ws;                  // bf16, 33.5 MB
  short* pq = (short*)((char*)d_ws + 33554432);                // packed qkv_w
  short* pp = pq + 12288;                                      // packed proj_w
  short* pi = pp + 4096;                                       // packed pin_w
  short* po = pi + 22528;                                      // packed pout_w

  prepack_kernel<<<dim3(88), dim3(256), 0, stream>>>(qkv_w, proj_w, pin_w, pout_w, pq, pp, pi, po);
  attn_kernel<<<dim3(4096), dim3(BLK), 0, stream>>>(x, ln1_w, ln1_b, qkv_dw, temp, proj_b, pq, pp, x1);
  ffn_kernel<<<dim3(4096), dim3(BLK), 0, stream>>>(x1, ln2_w, ln2_b, dw_w, pi, po, out);
}

// Round 5
// 518.894 us; speedup vs baseline: 3.0375x; 1.1004x over previous
//
#include <hip/hip_runtime.h>
#include <math.h>

typedef __attribute__((ext_vector_type(8))) short short8;
typedef __attribute__((ext_vector_type(4))) short s16x4;
typedef __attribute__((ext_vector_type(4))) float f32x4;

#define CC 64
#define HH 256
#define WW 256
#define HID 170
#define PLANE (HH*WW)

__device__ __forceinline__ unsigned short f2bf(float f) {
  unsigned u = __float_as_uint(f);
  u += 0x7FFFu + ((u >> 16) & 1u);
  return (unsigned short)(u >> 16);
}
__device__ __forceinline__ float bf2f(unsigned short h) {
  return __uint_as_float(((unsigned)h) << 16);
}
__device__ __forceinline__ float bf2f_lo(unsigned v) { return __uint_as_float(v << 16); }
__device__ __forceinline__ float bf2f_hi(unsigned v) { return __uint_as_float(v & 0xFFFF0000u); }

__device__ __forceinline__ f32x4 mfma16(short8 a, short8 b, f32x4 c) {
  return __builtin_amdgcn_mfma_f32_16x16x32_bf16(a, b, c, 0, 0, 0);
}
__device__ __forceinline__ uint2 pack4bf(f32x4 v) {
  uint2 r;
  r.x = (unsigned)f2bf(v[0]) | ((unsigned)f2bf(v[1]) << 16);
  r.y = (unsigned)f2bf(v[2]) | ((unsigned)f2bf(v[3]) << 16);
  return r;
}

// ======================= prepack (weights -> bf16 fragment order) ==========
__global__ void prepack_kernel(const float* __restrict__ qkv_w, const float* __restrict__ proj_w,
                               const float* __restrict__ pin_w, const float* __restrict__ pout_w,
                               short* __restrict__ pq, short* __restrict__ pp,
                               short* __restrict__ pi, short* __restrict__ po) {
  int idx = blockIdx.x * 256 + threadIdx.x;
  if (idx < 12288) {  // qkv: 12 mtiles x 2 ksteps
    int j = idx & 7, ln = (idx >> 3) & 63, ks = (idx >> 9) & 1, mt = idx >> 10;
    int row = mt * 16 + (ln & 15), k = ks * 32 + (ln >> 4) * 8 + j;
    pq[idx] = (short)f2bf(qkv_w[row * 64 + k]);
  }
  if (idx < 4096) {   // proj: 4 x 2
    int j = idx & 7, ln = (idx >> 3) & 63, ks = (idx >> 9) & 1, mt = idx >> 10;
    int row = mt * 16 + (ln & 15), k = ks * 32 + (ln >> 4) * 8 + j;
    pp[idx] = (short)f2bf(proj_w[row * 64 + k]);
  }
  if (idx < 22528) {  // pin: 22 x 2, rows re-ordered into gate-pair chunks
    int j = idx & 7, ln = (idx >> 3) & 63, ks = (idx >> 9) & 1, mt = idx >> 10;
    int r = mt * 16 + (ln & 15), k = ks * 32 + (ln >> 4) * 8 + j;
    int c = r >> 7; if (c > 2) c = 2;
    int loc = r - c * 128;
    int half = (c < 2) ? 64 : 48, limit = (c < 2) ? 64 : 42;
    float v = 0.f;
    if (loc < half) { int i = loc; if (i < limit) v = pin_w[(c * 64 + i) * 64 + k]; }
    else { int i = loc - half; if (i < limit) v = pin_w[(HID + c * 64 + i) * 64 + k]; }
    pi[idx] = (short)f2bf(v);
  }
  if (idx < 12288) {  // pout: 4 mtiles x 6 ksteps (K padded 170->192)
    int j = idx & 7, ln = (idx >> 3) & 63, ks = (idx >> 9) % 6, mt = idx / 3072;
    int o = mt * 16 + (ln & 15), k = ks * 32 + (ln >> 4) * 8 + j;
    float v = (k < 170) ? pout_w[o * 170 + k] : 0.f;
    po[idx] = (short)f2bf(v);
  }
}

// ======================= layernorm (NCHW f32 -> NHWC bf16) =================
__global__ __launch_bounds__(256) void ln_kernel(
    const float* __restrict__ src, const float* __restrict__ w,
    const float* __restrict__ bia, unsigned short* __restrict__ dst) {
  __shared__ float xT[64 * 65];
  const int t = threadIdx.x;
  const int g = blockIdx.x << 6;     // 64 positions per block (same row, same image)
  const int bi = g >> 16;
  const int hw = g & 65535;
  {
    int c = t >> 2, q = t & 3;
    const float* sp = src + ((size_t)(bi * 64 + c) << 16) + hw + q * 16;
    float4 v0 = *(const float4*)(sp);
    float4 v1 = *(const float4*)(sp + 4);
    float4 v2 = *(const float4*)(sp + 8);
    float4 v3 = *(const float4*)(sp + 12);
    float* row = xT + c * 65 + q * 16;
    row[0] = v0.x; row[1] = v0.y; row[2] = v0.z; row[3] = v0.w;
    row[4] = v1.x; row[5] = v1.y; row[6] = v1.z; row[7] = v1.w;
    row[8] = v2.x; row[9] = v2.y; row[10] = v2.z; row[11] = v2.w;
    row[12] = v3.x; row[13] = v3.y; row[14] = v3.z; row[15] = v3.w;
  }
  __syncthreads();
  const int p = t >> 2, q = t & 3;
  float s = 0.f, s2 = 0.f;
  float vv[16];
#pragma unroll
  for (int i = 0; i < 16; ++i) {
    float v = xT[(q * 16 + i) * 65 + p];
    vv[i] = v; s += v; s2 += v * v;
  }
  s += __shfl_xor(s, 1); s2 += __shfl_xor(s2, 1);
  s += __shfl_xor(s, 2); s2 += __shfl_xor(s2, 2);
  float mu = s * (1.f / 64.f);
  float var = s2 * (1.f / 64.f) - mu * mu;
  float rstd = rsqrtf(var + 1e-5f);
  short8 o0, o1;
#pragma unroll
  for (int i = 0; i < 8; ++i) {
    o0[i] = (short)f2bf((vv[i] - mu) * rstd * w[q * 16 + i] + bia[q * 16 + i]);
    o1[i] = (short)f2bf((vv[8 + i] - mu) * rstd * w[q * 16 + 8 + i] + bia[q * 16 + 8 + i]);
  }
  unsigned short* dp = dst + (size_t)(g + p) * 64 + q * 16;
  *(short8*)dp = o0;
  *(short8*)(dp + 8) = o1;
}

// ======================= attn kernel ========================================
#define A_QK    0        // 128 x 72 sh = 18432
#define A_VT    18432    // 64 x 72 sh = 9216
#define A_XN    27648    // 112 x 64 sh = 14336 (swizzled [pos][chan])
#define A_QKVT  41984    // 112 x 102 sh = 22848 (ends 64832)
#define A_SCL   41984    // 128 f32 (overlaps dead QKVT)
#define A_PP    42496    // 64 x 33 f32 = 8448
#define A_PB    50944    // 64 x 40 sh = 5120
#define A_OW    56064    // 64 x 72 sh = 9216
#define A_TOT   65280

__global__ __launch_bounds__(512) void attn_kernel(
    const unsigned short* __restrict__ xn1, const float* __restrict__ x,
    const float* __restrict__ qkv_dw, const float* __restrict__ temp,
    const float* __restrict__ proj_b,
    const short* __restrict__ pk_qkv, const short* __restrict__ pk_proj,
    float* __restrict__ x1out) {
  __shared__ __align__(16) char smem[A_TOT];
  short* qk   = (short*)(smem + A_QK);
  short* vt   = (short*)(smem + A_VT);
  short* xn   = (short*)(smem + A_XN);
  short* qkvt = (short*)(smem + A_QKVT);
  float* scl  = (float*)(smem + A_SCL);
  float* pP   = (float*)(smem + A_PP);
  short* pB   = (short*)(smem + A_PB);
  short* ow   = (short*)(smem + A_OW);

  const int tid = threadIdx.x;
  const int lane = tid & 63;
  const int wid = tid >> 6;
  const int blk = blockIdx.x;
  const int b = blk >> 10, wy = (blk >> 5) & 31, wx = blk & 31;
  const int gy0 = wy * 8 - 1, gx0 = wx * 8 - 1;
  const size_t nb = (size_t)b << 16;

  // P1: halo load from xn1 (NHWC bf16) -> swizzled LDS; rows 100..111 zero
  for (int u = tid; u < 896; u += 512) {
    int p = u >> 3, q = u & 7;
    short8 v = {0, 0, 0, 0, 0, 0, 0, 0};
    if (p < 100) {
      int py = p / 10, px = p - py * 10;
      int gy = gy0 + py, gx = gx0 + px;
      if ((unsigned)gy < 256u && (unsigned)gx < 256u)
        v = *(const short8*)(xn1 + ((nb + gy * 256 + gx) << 6) + q * 8);
    }
    *(short8*)(xn + p * 64 + ((q ^ (p & 7)) << 3)) = v;
  }
  __syncthreads();

  // P3: qkv GEMM + depthwise 3x3, two chunks of 96 channels
  for (int cc = 0; cc < 2; ++cc) {
    for (int f = wid; f < 42; f += 8) {   // 6 mtiles x 7 ntiles
      int mt = f / 7, nt = f - mt * 7;
      int gmt = cc * 6 + mt;
      f32x4 acc = {0.f, 0.f, 0.f, 0.f};
#pragma unroll
      for (int ks = 0; ks < 2; ++ks) {
        short8 a = *(const short8*)(pk_qkv + ((gmt * 2 + ks) * 64 + lane) * 8);
        int pos = nt * 16 + (lane & 15);
        short8 bb = *(const short8*)(xn + pos * 64 + (((ks * 4 + (lane >> 4)) ^ (pos & 7)) << 3));
        acc = mfma16(a, bb, acc);
      }
      int pos = nt * 16 + (lane & 15);
      int chb = mt * 16 + (lane >> 4) * 4;
      uint2 r = pack4bf(acc);
      unsigned* dp = (unsigned*)(qkvt + pos * 102 + chb);
      dp[0] = r.x; dp[1] = r.y;
    }
    __syncthreads();
    for (int idx = tid; idx < 3072; idx += 512) {  // 48 chan-pairs x 64 pos
      int pr = idx >> 6, wp = idx & 63;
      int hp = ((wp >> 3) + 1) * 10 + (wp & 7) + 1;
      int chl = pr * 2, chg = cc * 96 + chl;
      const float* w0 = qkv_dw + chg * 9;
      const float* w1 = w0 + 9;
      float a0 = 0.f, a1 = 0.f;
#pragma unroll
      for (int t9 = 0; t9 < 9; ++t9) {
        int off = (t9 / 3 - 1) * 10 + (t9 % 3 - 1);
        unsigned v = *(const unsigned*)(qkvt + (hp + off) * 102 + chl);
        a0 = fmaf(w0[t9], bf2f_lo(v), a0);
        a1 = fmaf(w1[t9], bf2f_hi(v), a1);
      }
      if (chg < 128) {
        qk[chg * 72 + wp] = (short)f2bf(a0);
        qk[(chg + 1) * 72 + wp] = (short)f2bf(a1);
      } else {
        unsigned pv = (unsigned)f2bf(a0) | ((unsigned)f2bf(a1) << 16);
        *(unsigned*)(vt + wp * 72 + (chg - 128)) = pv;
      }
    }
    __syncthreads();
  }

  // P4: inverse L2 norms (128 rows x 4 lanes)
  {
    int row = tid >> 2, q4 = tid & 3;
    const short* r = qk + row * 72 + q4 * 16;
    short8 v0 = *(const short8*)(r);
    short8 v1 = *(const short8*)(r + 8);
    float s = 0.f;
#pragma unroll
    for (int j = 0; j < 8; ++j) {
      float f0 = bf2f((unsigned short)v0[j]); s = fmaf(f0, f0, s);
      float f1 = bf2f((unsigned short)v1[j]); s = fmaf(f1, f1, s);
    }
    s += __shfl_xor(s, 1);
    s += __shfl_xor(s, 2);
    if (q4 == 0) scl[row] = 1.f / fmaxf(sqrtf(s), 1e-12f);
  }
  __syncthreads();

  // P5: QK^T logits (one 16x16 frag per wave)
  {
    int h = wid >> 2, mt = (wid >> 1) & 1, nt = wid & 1;
    int arow = h * 32 + mt * 16;
    int brow = 64 + h * 32 + nt * 16;
    f32x4 acc = {0.f, 0.f, 0.f, 0.f};
#pragma unroll
    for (int ks = 0; ks < 2; ++ks) {
      short8 a = *(const short8*)(qk + (arow + (lane & 15)) * 72 + ks * 32 + (lane >> 4) * 8);
      short8 bb = *(const short8*)(qk + (brow + (lane & 15)) * 72 + ks * 32 + (lane >> 4) * 8);
      acc = mfma16(a, bb, acc);
    }
    float tf = temp[h];
    int e = nt * 16 + (lane & 15);
    float se = scl[64 + h * 32 + e] * tf;
    int cqb = h * 32 + mt * 16 + (lane >> 4) * 4;
#pragma unroll
    for (int j = 0; j < 4; ++j)
      pP[(cqb + j) * 33 + e] = acc[j] * scl[cqb + j] * se;
  }
  __syncthreads();

  // P6: softmax (64 rows x 8 lanes)
  {
    int row = tid >> 3, l = tid & 7;
    const float* rp = pP + row * 33 + l * 4;
    float e0 = rp[0], e1 = rp[1], e2 = rp[2], e3 = rp[3];
    float m = fmaxf(fmaxf(e0, e1), fmaxf(e2, e3));
    m = fmaxf(m, __shfl_xor(m, 1));
    m = fmaxf(m, __shfl_xor(m, 2));
    m = fmaxf(m, __shfl_xor(m, 4));
    float x0 = __expf(e0 - m), x1v = __expf(e1 - m);
    float x2 = __expf(e2 - m), x3 = __expf(e3 - m);
    float s = x0 + x1v + x2 + x3;
    s += __shfl_xor(s, 1);
    s += __shfl_xor(s, 2);
    s += __shfl_xor(s, 4);
    float inv = 1.f / s;
    s16x4 o;
    o[0] = (short)f2bf(x0 * inv); o[1] = (short)f2bf(x1v * inv);
    o[2] = (short)f2bf(x2 * inv); o[3] = (short)f2bf(x3 * inv);
    *(s16x4*)(pB + row * 40 + l * 4) = o;
  }
  __syncthreads();

  // P7: PV (16 frags, 2 per wave)
#pragma unroll
  for (int r = 0; r < 2; ++r) {
    int f = wid + r * 8;
    int h = f >> 3, mt = (f >> 2) & 1, nt = f & 3;
    short8 a = *(const short8*)(pB + (h * 32 + mt * 16 + (lane & 15)) * 40 + (lane >> 4) * 8);
    short8 bb = *(const short8*)(vt + (nt * 16 + (lane & 15)) * 72 + h * 32 + (lane >> 4) * 8);
    f32x4 acc = {0.f, 0.f, 0.f, 0.f};
    acc = mfma16(a, bb, acc);
    int d = nt * 16 + (lane & 15);
    int chb = h * 32 + mt * 16 + (lane >> 4) * 4;
    *(uint2*)(ow + d * 72 + chb) = pack4bf(acc);
  }
  __syncthreads();

  // P8: proj + bias + residual(x fp32) -> d_out fp32 (x1)
#pragma unroll
  for (int r = 0; r < 2; ++r) {
    int f = wid + r * 8;
    int mt = f >> 2, nt = f & 3;
    f32x4 acc = {0.f, 0.f, 0.f, 0.f};
#pragma unroll
    for (int ks = 0; ks < 2; ++ks) {
      short8 a = *(const short8*)(pk_proj + ((mt * 2 + ks) * 64 + lane) * 8);
      short8 bb = *(const short8*)(ow + (nt * 16 + (lane & 15)) * 72 + ks * 32 + (lane >> 4) * 8);
      acc = mfma16(a, bb, acc);
    }
    int pos = nt * 16 + (lane & 15);
    int gy = wy * 8 + (pos >> 3), gx = wx * 8 + (pos & 7);
    int ob = mt * 16 + (lane >> 4) * 4;
#pragma unroll
    for (int j = 0; j < 4; ++j) {
      int o = ob + j;
      size_t gp = (size_t)(b * CC + o) * PLANE + gy * WW + gx;
      x1out[gp] = acc[j] + proj_b[o] + x[gp];
    }
  }
}

// ======================= ffn kernel =========================================
#define F_Y12 0       // 112 x 134 sh = 30016
#define F_XN  30016   // 112 x 64 sh = 14336
#define F_G   44352   // 64 x 72 sh = 9216
#define F_TOT 53568

__global__ __launch_bounds__(512) void ffn_kernel(
    const unsigned short* __restrict__ xn2,
    const float* __restrict__ dw_w,
    const short* __restrict__ pk_pin, const short* __restrict__ pk_pout,
    float* __restrict__ out) {
  __shared__ __align__(16) char smem[F_TOT];
  short* y12 = (short*)(smem + F_Y12);
  short* xn  = (short*)(smem + F_XN);
  short* g   = (short*)(smem + F_G);

  const int tid = threadIdx.x;
  const int lane = tid & 63;
  const int wid = tid >> 6;
  const int blk = blockIdx.x;
  const int b = blk >> 10, wy = (blk >> 5) & 31, wx = blk & 31;
  const int gy0 = wy * 8 - 1, gx0 = wx * 8 - 1;
  const size_t nb = (size_t)b << 16;

  // P1: halo load from xn2 (NHWC bf16) -> swizzled LDS
  for (int u = tid; u < 896; u += 512) {
    int p = u >> 3, q = u & 7;
    short8 v = {0, 0, 0, 0, 0, 0, 0, 0};
    if (p < 100) {
      int py = p / 10, px = p - py * 10;
      int gy = gy0 + py, gx = gx0 + px;
      if ((unsigned)gy < 256u && (unsigned)gx < 256u)
        v = *(const short8*)(xn2 + ((nb + gy * 256 + gx) << 6) + q * 8);
    }
    *(short8*)(xn + p * 64 + ((q ^ (p & 7)) << 3)) = v;
  }
  __syncthreads();

  f32x4 acc0 = {0.f, 0.f, 0.f, 0.f}, acc1 = {0.f, 0.f, 0.f, 0.f};

  for (int cc2 = 0; cc2 < 3; ++cc2) {
    const int MT = (cc2 < 2) ? 8 : 6;
    const int mbase = cc2 * 8;
    // pin GEMM chunk -> y12 [pos][chan] stride 134
    for (int f = wid; f < MT * 7; f += 8) {
      int mt = f / 7, nt = f - mt * 7;
      int gmt = mbase + mt;
      f32x4 acc = {0.f, 0.f, 0.f, 0.f};
#pragma unroll
      for (int ks = 0; ks < 2; ++ks) {
        short8 a = *(const short8*)(pk_pin + ((gmt * 2 + ks) * 64 + lane) * 8);
        int pos = nt * 16 + (lane & 15);
        short8 bb = *(const short8*)(xn + pos * 64 + (((ks * 4 + (lane >> 4)) ^ (pos & 7)) << 3));
        acc = mfma16(a, bb, acc);
      }
      int pos = nt * 16 + (lane & 15);
      int chb = mt * 16 + (lane >> 4) * 4;
      uint2 r = pack4bf(acc);
      unsigned* dp = (unsigned*)(y12 + pos * 134 + chb);
      dp[0] = r.x; dp[1] = r.y;
    }
    __syncthreads();
    // dwconv + exact-GELU gate -> g [pos][i] stride 72
    const int half = (cc2 < 2) ? 64 : 48;
    const int npg = half >> 1;
    for (int idx = tid; idx < npg * 64; idx += 512) {
      int pr = idx >> 6, wp = idx & 63;
      int hp = ((wp >> 3) + 1) * 10 + (wp & 7) + 1;
      int i0 = pr * 2;
      const float* wa = dw_w + (64 * cc2 + i0) * 9;
      const float* wb = wa + 9;
      const float* wc = dw_w + (HID + 64 * cc2 + i0) * 9;
      const float* wdd = wc + 9;
      float a0 = 0.f, a1 = 0.f, b0 = 0.f, b1 = 0.f;
#pragma unroll
      for (int t9 = 0; t9 < 9; ++t9) {
        int off = (t9 / 3 - 1) * 10 + (t9 % 3 - 1);
        unsigned v1 = *(const unsigned*)(y12 + (hp + off) * 134 + i0);
        unsigned v2 = *(const unsigned*)(y12 + (hp + off) * 134 + half + i0);
        a0 = fmaf(wa[t9], bf2f_lo(v1), a0);
        a1 = fmaf(wb[t9], bf2f_hi(v1), a1);
        b0 = fmaf(wc[t9], bf2f_lo(v2), b0);
        b1 = fmaf(wdd[t9], bf2f_hi(v2), b1);
      }
      float g0 = 0.5f * a0 * (1.f + erff(a0 * 0.70710678118654752f)) * b0;
      float g1 = 0.5f * a1 * (1.f + erff(a1 * 0.70710678118654752f)) * b1;
      unsigned pv = (unsigned)f2bf(g0) | ((unsigned)f2bf(g1) << 16);
      *(unsigned*)(g + wp * 72 + i0) = pv;
    }
    __syncthreads();
    // pout partial GEMM (accumulate across chunks in registers)
    {
      int f0 = wid;
      int mt = f0 >> 2, nt = f0 & 3;
#pragma unroll
      for (int ks = 0; ks < 2; ++ks) {
        int gks = cc2 * 2 + ks;
        short8 a = *(const short8*)(pk_pout + ((mt * 6 + gks) * 64 + lane) * 8);
        short8 bb = *(const short8*)(g + (nt * 16 + (lane & 15)) * 72 + ks * 32 + (lane >> 4) * 8);
        acc0 = mfma16(a, bb, acc0);
      }
      int f1 = wid + 8;
      mt = f1 >> 2; nt = f1 & 3;
#pragma unroll
      for (int ks = 0; ks < 2; ++ks) {
        int gks = cc2 * 2 + ks;
        short8 a = *(const short8*)(pk_pout + ((mt * 6 + gks) * 64 + lane) * 8);
        short8 bb = *(const short8*)(g + (nt * 16 + (lane & 15)) * 72 + ks * 32 + (lane >> 4) * 8);
        acc1 = mfma16(a, bb, acc1);
      }
    }
    __syncthreads();
  }

  // epilogue: in-place residual RMW on d_out
#pragma unroll
  for (int r = 0; r < 2; ++r) {
    int f = wid + r * 8;
    int mt = f >> 2, nt = f & 3;
    f32x4 acc = r ? acc1 : acc0;
    int pos = nt * 16 + (lane & 15);
    int gy = wy * 8 + (pos >> 3), gx = wx * 8 + (pos & 7);
    int ob = mt * 16 + (lane >> 4) * 4;
#pragma unroll
    for (int j = 0; j < 4; ++j) {
      int o = ob + j;
      size_t gp = (size_t)(b * CC + o) * PLANE + gy * WW + gx;
      out[gp] = acc[j] + out[gp];
    }
  }
}

// ======================= launch =============================================
extern "C" void kernel_launch(void* const* d_in, const int* in_sizes, int n_in,
                              void* d_out, int out_size, void* d_ws, size_t ws_size,
                              hipStream_t stream) {
  const float* x      = (const float*)d_in[0];
  const float* ln1_w  = (const float*)d_in[1];
  const float* ln1_b  = (const float*)d_in[2];
  const float* qkv_w  = (const float*)d_in[3];
  const float* qkv_dw = (const float*)d_in[4];
  const float* temp   = (const float*)d_in[5];
  const float* proj_w = (const float*)d_in[6];
  const float* proj_b = (const float*)d_in[7];
  const float* ln2_w  = (const float*)d_in[8];
  const float* ln2_b  = (const float*)d_in[9];
  const float* pin_w  = (const float*)d_in[10];
  const float* dw_w   = (const float*)d_in[11];
  const float* pout_w = (const float*)d_in[12];
  float* out = (float*)d_out;

  unsigned short* xnbuf = (unsigned short*)d_ws;           // bf16 NHWC, 33.5 MB
  short* pq = (short*)((char*)d_ws + 33554432);
  short* pp = pq + 12288;
  short* pi = pp + 4096;
  short* po = pi + 22528;

  prepack_kernel<<<dim3(88), dim3(256), 0, stream>>>(qkv_w, proj_w, pin_w, pout_w, pq, pp, pi, po);
  ln_kernel<<<dim3(4096), dim3(256), 0, stream>>>(x, ln1_w, ln1_b, xnbuf);
  attn_kernel<<<dim3(4096), dim3(512), 0, stream>>>(xnbuf, x, qkv_dw, temp, proj_b, pq, pp, out);
  ln_kernel<<<dim3(4096), dim3(256), 0, stream>>>(out, ln2_w, ln2_b, xnbuf);
  ffn_kernel<<<dim3(4096), dim3(512), 0, stream>>>(xnbuf, dw_w, pi, po, out);
}